// Round 13
// baseline (344.444 us; speedup 1.0000x reference)
//
#include <hip/hip_runtime.h>

// R13: fit the 128-reg tier instead of fighting it.
//  - 512-thread block (8 waves) + ONE 64 KB LDS slab (W2|W3) -> 8 waves/CU,
//    2 waves/SIMD guaranteed at 1 block/CU. R9 proved 512-thread blocks raise
//    occupancy; it lost only to spill because 512-thread => 128-reg tier.
//  - T=2 + paired-nt accumulation keeps peak live ~125 regs <= 128: B1 32 +
//    B2 32 + acc 16 + px 12 + transients. No spill expected.
//  - L1/L4 compact frags + biases from global (L1/L2-hot, VMEM pipe).
// Expected regime: MFMA ~94k cyc/SIMD, LDS ~98k cyc/CU, VALU ~40k -> wall
// ~max ≈ 45-55 us when 2 waves/SIMD overlap (was ~sum at 1 wave/SIMD).
//
// ws layout (bytes) — written by nerf_stage (same as R12):
//   0     : W2 frags, 32 x 1024   (f = ks*8+nt; lane l at f*1024 + l*16)
//   32768 : W3 frags, 32 x 1024
//   65536 : L1 compact, 8 x 256   (frag nt, slot n: j<6 -> W1[(nt*16+n)*6+j],
//                                  j==6 -> b1[nt*16+n], j==7 -> 0)
//   67584 : L4 compact, 4 x 256   (frag ks, slot s=q*4+outrow)
//   68608 : zeros, 2048
//   70656 : bias2 = b2[0..127]    (f32x4 entry nt*4+q)
//   71168 : bias3 = b3[0..127]
//   71680 : b4 padded (q==0 -> b4[0..3], else 0)

typedef __attribute__((ext_vector_type(8))) short short8;
typedef __attribute__((ext_vector_type(4))) float f32x4;
typedef __attribute__((ext_vector_type(2))) float f32x2;
typedef __attribute__((ext_vector_type(4))) unsigned int u32x4;

#define MFMA(a, b, c) __builtin_amdgcn_mfma_f32_16x16x32_bf16((a), (b), (c), 0, 0, 0)

__device__ __forceinline__ unsigned short bfr(float f) {  // fp32->bf16 RNE
  unsigned u = __builtin_bit_cast(unsigned, f);
  u += 0x7FFFu + ((u >> 16) & 1u);
  return (unsigned short)(u >> 16);
}

__device__ __forceinline__ unsigned pkrelu(float a, float b) {
  a = __builtin_fmaxf(a, 0.f);
  b = __builtin_fmaxf(b, 0.f);
#if __has_builtin(__builtin_amdgcn_cvt_pk_bf16_f32)
  auto h = __builtin_amdgcn_cvt_pk_bf16_f32(a, b);
  return __builtin_bit_cast(unsigned, h);
#else
  unsigned ia = __builtin_bit_cast(unsigned, a) + 0x8000u;
  unsigned ib = __builtin_bit_cast(unsigned, b) + 0x8000u;
#if __has_builtin(__builtin_amdgcn_perm)
  return __builtin_amdgcn_perm(ib, ia, 0x07060302u);
#else
  return (ia >> 16) | (ib & 0xFFFF0000u);
#endif
#endif
}

__device__ __forceinline__ short8 pack4(const f32x4& a0, const f32x4& a1) {
  u32x4 u;
  u.x = pkrelu(a0.x, a0.y);
  u.y = pkrelu(a0.z, a0.w);
  u.z = pkrelu(a1.x, a1.y);
  u.w = pkrelu(a1.z, a1.w);
  return __builtin_bit_cast(short8, u);
}

// consumer B k-slot kp <- producer neuron slot sig_inv(kp)
__device__ __forceinline__ int sig_inv(int kp) {
  return ((kp >> 5) << 5) + (((kp >> 2) & 1) << 4) + (((kp >> 3) & 3) << 2) + (kp & 3);
}

__global__ void nerf_stage(const float* __restrict__ W1, const float* __restrict__ b1,
                           const float* __restrict__ W2, const float* __restrict__ b2,
                           const float* __restrict__ W3, const float* __restrict__ b3,
                           const float* __restrict__ W4, const float* __restrict__ b4,
                           void* __restrict__ ws) {
  unsigned short* wf = (unsigned short*)ws;
  const int idx = blockIdx.x * 256 + threadIdx.x;
  const int stride = gridDim.x * 256;

  // W2 (f 0..31) and W3 (f 32..63) full frags
  for (int p = idx; p < 64 * 64; p += stride) {
    const int f = p >> 6, l = p & 63, m = l & 15, q = l >> 4;
    const int g = f & 31, ks = g >> 3, nt = g & 7;
    const float* W = (f < 32) ? W2 : W3;
    unsigned short v[8];
#pragma unroll
    for (int j = 0; j < 8; ++j)
      v[j] = bfr(W[(nt * 16 + m) * 128 + sig_inv(ks * 32 + q * 8 + j)]);
#pragma unroll
    for (int j = 0; j < 8; ++j) wf[f * 512 + l * 8 + j] = v[j];
  }

  // L1 compact: 8 frags x 16 slots at byte 65536
  for (int e = idx; e < 128; e += stride) {
    const int nt = e >> 4, n = e & 15;
    unsigned short v[8];
#pragma unroll
    for (int j = 0; j < 8; ++j) {
      float val = 0.f;
      if (j < 6) val = W1[(nt * 16 + n) * 6 + j];
      else if (j == 6) val = b1[nt * 16 + n];
      v[j] = bfr(val);
    }
#pragma unroll
    for (int j = 0; j < 8; ++j) wf[(65536 >> 1) + e * 8 + j] = v[j];
  }

  // L4 compact: 4 frags x 16 slots (s = q*4 + outrow) at byte 67584
  for (int e = idx; e < 64; e += stride) {
    const int ks = e >> 4, s = e & 15, q = s >> 2, n = s & 3;
    unsigned short v[8];
#pragma unroll
    for (int j = 0; j < 8; ++j)
      v[j] = bfr(W4[n * 128 + sig_inv(ks * 32 + q * 8 + j)]);
#pragma unroll
    for (int j = 0; j < 8; ++j) wf[(67584 >> 1) + e * 8 + j] = v[j];
  }

  // zeros at byte 68608 (ws is poisoned 0xAA each launch -> must clear)
  {
    float* z = (float*)((char*)ws + 68608);
    for (int e = idx; e < 512; e += stride) z[e] = 0.f;
  }

  // biases at byte 70656: b2 | b3 | b4 padded
  {
    float* wb = (float*)((char*)ws + 70656);
    for (int e = idx; e < 272; e += stride) {
      float val;
      if (e < 128) val = b2[e];
      else if (e < 256) val = b3[e - 128];
      else val = ((e & 15) < 4) ? b4[e & 3] : 0.f;
      wb[e] = val;
    }
  }
}

__launch_bounds__(512)
__global__ void nerf_main(const float* __restrict__ x, float* __restrict__ out,
                          const void* __restrict__ ws, int nGroups) {
  __shared__ __align__(16) unsigned short lds[32768];  // exactly 65536 B: W2 | W3

  {  // copy W2/W3 frags only: 65536/16 = 4096 16B chunks
    const u32x4* src = (const u32x4*)ws;
    u32x4* dst = (u32x4*)lds;
    for (int i = threadIdx.x; i < 4096; i += 512) dst[i] = src[i];
  }
  __syncthreads();

  const int lane = threadIdx.x & 63;
  const int wid = threadIdx.x >> 6;
  const int q = lane >> 4;
  const int n = lane & 15;

  const int waveId = blockIdx.x * 8 + wid;
  const int totalWaves = gridDim.x * 8;

  // LDS bases (frag index in the offset)
  const unsigned short* w2b = lds + lane * 8;            // + (ks*8+nt)*512
  const unsigned short* w3b = lds + 16384 + lane * 8;    // + (ks*8+nt)*512

  // global (L1/L2-hot) bases for extras — lane-conditional into zeros region.
  // Compact frag stride = 256 B = 16 short8.
  const char* wsb = (const char*)ws;
  const short8* l1g = (const short8*)(wsb + ((q == 0) ? 65536 : 68608) + n * 16);  // + nt*16
  const short8* l4g = (const short8*)(
      wsb + ((n < 4) ? (67584 + (q * 4 + n) * 16) : (68608 + n * 16)));            // + ks*16
  const f32x4* bias2 = (const f32x4*)(wsb + 70656) + q;  // + nt*4
  const f32x4* bias3 = (const f32x4*)(wsb + 71168) + q;  // + nt*4
  const f32x4* b4p   = (const f32x4*)(wsb + 71680) + q;

  const f32x4 zf = {0.f, 0.f, 0.f, 0.f};

  float px[2][6] = {};
  int g = waveId;
  if (g < nGroups && q == 0) {
#pragma unroll
    for (int t = 0; t < 2; ++t) {
      const float* p = x + (g * 32 + t * 16 + n) * 6;
      f32x2 a = *(const f32x2*)p, b = *(const f32x2*)(p + 2), c = *(const f32x2*)(p + 4);
      px[t][0] = a.x; px[t][1] = a.y; px[t][2] = b.x;
      px[t][3] = b.y; px[t][4] = c.x; px[t][5] = c.y;
    }
  }

  for (; g < nGroups; g += totalWaves) {
    // ---- x -> layer-1 B frags (q==0: k0..5 = x, k6 = 1.0 bias slot) ----
    short8 xb[2];
#pragma unroll
    for (int t = 0; t < 2; ++t) {
      short8 v = {0, 0, 0, 0, 0, 0, 0, 0};
      if (q == 0) {
        v[0] = (short)bfr(px[t][0]); v[1] = (short)bfr(px[t][1]);
        v[2] = (short)bfr(px[t][2]); v[3] = (short)bfr(px[t][3]);
        v[4] = (short)bfr(px[t][4]); v[5] = (short)bfr(px[t][5]);
        v[6] = (short)0x3F80;  // bf16 1.0
      }
      xb[t] = v;
    }
    const int gn = g + totalWaves;
    if (gn < nGroups && q == 0) {
#pragma unroll
      for (int t = 0; t < 2; ++t) {
        const float* p = x + (gn * 32 + t * 16 + n) * 6;
        f32x2 a = *(const f32x2*)p, b = *(const f32x2*)(p + 2), c = *(const f32x2*)(p + 4);
        px[t][0] = a.x; px[t][1] = a.y; px[t][2] = b.x;
        px[t][3] = b.y; px[t][4] = c.x; px[t][5] = c.y;
      }
    }

    short8 B1[2][4], B2[2][4];

    // ---- layer 1 (compact frags from global/L2; bias in k-slot 6; C=0) ----
#pragma unroll
    for (int ntp = 0; ntp < 4; ++ntp) {
      const short8 w0 = l1g[(2 * ntp) * 16];
      const short8 w1 = l1g[(2 * ntp + 1) * 16];
      f32x4 a0[2], a1[2];
#pragma unroll
      for (int t = 0; t < 2; ++t) {
        a0[t] = MFMA(w0, xb[t], zf);
        a1[t] = MFMA(w1, xb[t], zf);
      }
#pragma unroll
      for (int t = 0; t < 2; ++t) B1[t][ntp] = pack4(a0[t], a1[t]);
    }

    // ---- layer 2 (W2 frags from LDS; bias as C at ks==0) ----
#pragma unroll
    for (int ntp = 0; ntp < 4; ++ntp) {
      f32x4 a0[2], a1[2];
#pragma unroll
      for (int ks = 0; ks < 4; ++ks) {
        const short8 w0 = *(const short8*)(w2b + (ks * 8 + 2 * ntp) * 512);
        const short8 w1 = *(const short8*)(w2b + (ks * 8 + 2 * ntp + 1) * 512);
        if (ks == 0) {
          const f32x4 bv0 = bias2[(2 * ntp) * 4];
          const f32x4 bv1 = bias2[(2 * ntp + 1) * 4];
#pragma unroll
          for (int t = 0; t < 2; ++t) {
            a0[t] = MFMA(w0, B1[t][0], bv0);
            a1[t] = MFMA(w1, B1[t][0], bv1);
          }
        } else {
#pragma unroll
          for (int t = 0; t < 2; ++t) {
            a0[t] = MFMA(w0, B1[t][ks], a0[t]);
            a1[t] = MFMA(w1, B1[t][ks], a1[t]);
          }
        }
      }
#pragma unroll
      for (int t = 0; t < 2; ++t) B2[t][ntp] = pack4(a0[t], a1[t]);
    }

    // ---- layer 3 (W3 frags from LDS) ----
#pragma unroll
    for (int ntp = 0; ntp < 4; ++ntp) {
      f32x4 a0[2], a1[2];
#pragma unroll
      for (int ks = 0; ks < 4; ++ks) {
        const short8 w0 = *(const short8*)(w3b + (ks * 8 + 2 * ntp) * 512);
        const short8 w1 = *(const short8*)(w3b + (ks * 8 + 2 * ntp + 1) * 512);
        if (ks == 0) {
          const f32x4 bv0 = bias3[(2 * ntp) * 4];
          const f32x4 bv1 = bias3[(2 * ntp + 1) * 4];
#pragma unroll
          for (int t = 0; t < 2; ++t) {
            a0[t] = MFMA(w0, B2[t][0], bv0);
            a1[t] = MFMA(w1, B2[t][0], bv1);
          }
        } else {
#pragma unroll
          for (int t = 0; t < 2; ++t) {
            a0[t] = MFMA(w0, B2[t][ks], a0[t]);
            a1[t] = MFMA(w1, B2[t][ks], a1[t]);
          }
        }
      }
#pragma unroll
      for (int t = 0; t < 2; ++t) B1[t][ntp] = pack4(a0[t], a1[t]);  // reuse B1
    }

    // ---- layer 4 (compact frags from global/L2; out rows at q==0) ----
    f32x4 o[2];
    {
      const f32x4 bv = b4p[0];
#pragma unroll
      for (int ks = 0; ks < 4; ++ks) {
        const short8 w = l4g[ks * 16];
        if (ks == 0) {
#pragma unroll
          for (int t = 0; t < 2; ++t) o[t] = MFMA(w, B1[t][0], bv);
        } else {
#pragma unroll
          for (int t = 0; t < 2; ++t) o[t] = MFMA(w, B1[t][ks], o[t]);
        }
      }
    }
    if (q == 0) {
#pragma unroll
      for (int t = 0; t < 2; ++t)
        *(f32x4*)(out + (g * 32 + t * 16 + n) * 4) = o[t];
    }
  }
}

extern "C" void kernel_launch(void* const* d_in, const int* in_sizes, int n_in,
                              void* d_out, int out_size, void* d_ws, size_t ws_size,
                              hipStream_t stream) {
  const float* x  = (const float*)d_in[0];
  const float* W1 = (const float*)d_in[1];
  const float* b1 = (const float*)d_in[2];
  const float* W2 = (const float*)d_in[3];
  const float* b2 = (const float*)d_in[4];
  const float* W3 = (const float*)d_in[5];
  const float* b3 = (const float*)d_in[6];
  const float* W4 = (const float*)d_in[7];
  const float* b4 = (const float*)d_in[8];
  float* out = (float*)d_out;

  const int N = in_sizes[0] / 6;
  const int nGroups = N / 32;  // 2 tiles of 16 rows per wave-iteration -> 32768

  nerf_stage<<<dim3(4), dim3(256), 0, stream>>>(W1, b1, W2, b2, W3, b3, W4, b4, d_ws);

  // 256 blocks x 8 waves = 2048 waves; 1 block/CU, 2 waves/SIMD; 16 iters/wave
  nerf_main<<<dim3(256), dim3(512), 0, stream>>>(x, out, d_ws, nGroups);
}

// Round 14
// 161.057 us; speedup vs baseline: 2.1386x; 2.1386x over previous
//
#include <hip/hip_runtime.h>

// R14 = R13 + anti-hoist laundering of the extras base pointer.
// R13 proved the occupancy law (VGPR 256 -> 1 wave/SIMD; 128 -> 2/SIMD; LDS
// never the blocker) but spilled: the compiler HOISTED the loop-invariant
// global extras loads (L1/L4 frags + biases, ~116 regs worth) into the
// 128-reg budget, spilling B-frags (FETCH 864 MB / WRITE 123 MB).
// Fix: launder the ws base pointer through an empty asm inside the loop so
// extras addresses are loop-variant -> loads stay in the loop (L2-hot,
// ~21 x 16 B/lane/iter, the R12-proven-cheap path), steady-state live set
// ~126 regs fits the tier.
//
// ws layout (bytes) — written by nerf_stage (same as R12/R13):
//   0     : W2 frags, 32 x 1024   (f = ks*8+nt; lane l at f*1024 + l*16)
//   32768 : W3 frags, 32 x 1024
//   65536 : L1 compact, 8 x 256   (frag nt, slot n: j<6 -> W1[(nt*16+n)*6+j],
//                                  j==6 -> b1[nt*16+n], j==7 -> 0)
//   67584 : L4 compact, 4 x 256   (frag ks, slot s=q*4+outrow)
//   68608 : zeros, 2048
//   70656 : bias2 = b2[0..127]    (f32x4 entry nt*4+q)
//   71168 : bias3 = b3[0..127]
//   71680 : b4 padded (q==0 -> b4[0..3], else 0)

typedef __attribute__((ext_vector_type(8))) short short8;
typedef __attribute__((ext_vector_type(4))) float f32x4;
typedef __attribute__((ext_vector_type(2))) float f32x2;
typedef __attribute__((ext_vector_type(4))) unsigned int u32x4;

#define MFMA(a, b, c) __builtin_amdgcn_mfma_f32_16x16x32_bf16((a), (b), (c), 0, 0, 0)

__device__ __forceinline__ unsigned short bfr(float f) {  // fp32->bf16 RNE
  unsigned u = __builtin_bit_cast(unsigned, f);
  u += 0x7FFFu + ((u >> 16) & 1u);
  return (unsigned short)(u >> 16);
}

__device__ __forceinline__ unsigned pkrelu(float a, float b) {
  a = __builtin_fmaxf(a, 0.f);
  b = __builtin_fmaxf(b, 0.f);
#if __has_builtin(__builtin_amdgcn_cvt_pk_bf16_f32)
  auto h = __builtin_amdgcn_cvt_pk_bf16_f32(a, b);
  return __builtin_bit_cast(unsigned, h);
#else
  unsigned ia = __builtin_bit_cast(unsigned, a) + 0x8000u;
  unsigned ib = __builtin_bit_cast(unsigned, b) + 0x8000u;
#if __has_builtin(__builtin_amdgcn_perm)
  return __builtin_amdgcn_perm(ib, ia, 0x07060302u);
#else
  return (ia >> 16) | (ib & 0xFFFF0000u);
#endif
#endif
}

__device__ __forceinline__ short8 pack4(const f32x4& a0, const f32x4& a1) {
  u32x4 u;
  u.x = pkrelu(a0.x, a0.y);
  u.y = pkrelu(a0.z, a0.w);
  u.z = pkrelu(a1.x, a1.y);
  u.w = pkrelu(a1.z, a1.w);
  return __builtin_bit_cast(short8, u);
}

// consumer B k-slot kp <- producer neuron slot sig_inv(kp)
__device__ __forceinline__ int sig_inv(int kp) {
  return ((kp >> 5) << 5) + (((kp >> 2) & 1) << 4) + (((kp >> 3) & 3) << 2) + (kp & 3);
}

__global__ void nerf_stage(const float* __restrict__ W1, const float* __restrict__ b1,
                           const float* __restrict__ W2, const float* __restrict__ b2,
                           const float* __restrict__ W3, const float* __restrict__ b3,
                           const float* __restrict__ W4, const float* __restrict__ b4,
                           void* __restrict__ ws) {
  unsigned short* wf = (unsigned short*)ws;
  const int idx = blockIdx.x * 256 + threadIdx.x;
  const int stride = gridDim.x * 256;

  // W2 (f 0..31) and W3 (f 32..63) full frags
  for (int p = idx; p < 64 * 64; p += stride) {
    const int f = p >> 6, l = p & 63, m = l & 15, q = l >> 4;
    const int g = f & 31, ks = g >> 3, nt = g & 7;
    const float* W = (f < 32) ? W2 : W3;
    unsigned short v[8];
#pragma unroll
    for (int j = 0; j < 8; ++j)
      v[j] = bfr(W[(nt * 16 + m) * 128 + sig_inv(ks * 32 + q * 8 + j)]);
#pragma unroll
    for (int j = 0; j < 8; ++j) wf[f * 512 + l * 8 + j] = v[j];
  }

  // L1 compact: 8 frags x 16 slots at byte 65536
  for (int e = idx; e < 128; e += stride) {
    const int nt = e >> 4, n = e & 15;
    unsigned short v[8];
#pragma unroll
    for (int j = 0; j < 8; ++j) {
      float val = 0.f;
      if (j < 6) val = W1[(nt * 16 + n) * 6 + j];
      else if (j == 6) val = b1[nt * 16 + n];
      v[j] = bfr(val);
    }
#pragma unroll
    for (int j = 0; j < 8; ++j) wf[(65536 >> 1) + e * 8 + j] = v[j];
  }

  // L4 compact: 4 frags x 16 slots (s = q*4 + outrow) at byte 67584
  for (int e = idx; e < 64; e += stride) {
    const int ks = e >> 4, s = e & 15, q = s >> 2, n = s & 3;
    unsigned short v[8];
#pragma unroll
    for (int j = 0; j < 8; ++j)
      v[j] = bfr(W4[n * 128 + sig_inv(ks * 32 + q * 8 + j)]);
#pragma unroll
    for (int j = 0; j < 8; ++j) wf[(67584 >> 1) + e * 8 + j] = v[j];
  }

  // zeros at byte 68608 (ws is poisoned 0xAA each launch -> must clear)
  {
    float* z = (float*)((char*)ws + 68608);
    for (int e = idx; e < 512; e += stride) z[e] = 0.f;
  }

  // biases at byte 70656: b2 | b3 | b4 padded
  {
    float* wb = (float*)((char*)ws + 70656);
    for (int e = idx; e < 272; e += stride) {
      float val;
      if (e < 128) val = b2[e];
      else if (e < 256) val = b3[e - 128];
      else val = ((e & 15) < 4) ? b4[e & 3] : 0.f;
      wb[e] = val;
    }
  }
}

__launch_bounds__(512)
__global__ void nerf_main(const float* __restrict__ x, float* __restrict__ out,
                          const void* __restrict__ ws, int nGroups) {
  __shared__ __align__(16) unsigned short lds[32768];  // exactly 65536 B: W2 | W3

  {  // copy W2/W3 frags only: 65536/16 = 4096 16B chunks
    const u32x4* src = (const u32x4*)ws;
    u32x4* dst = (u32x4*)lds;
    for (int i = threadIdx.x; i < 4096; i += 512) dst[i] = src[i];
  }
  __syncthreads();

  const int lane = threadIdx.x & 63;
  const int wid = threadIdx.x >> 6;
  const int q = lane >> 4;
  const int n = lane & 15;

  const int waveId = blockIdx.x * 8 + wid;
  const int totalWaves = gridDim.x * 8;

  // LDS bases (frag index in the offset)
  const unsigned short* w2b = lds + lane * 8;            // + (ks*8+nt)*512
  const unsigned short* w3b = lds + 16384 + lane * 8;    // + (ks*8+nt)*512

  // lane-conditional byte offsets for the extras (bases derived per-iteration
  // from the laundered pointer so the loads cannot be hoisted out of the loop)
  const int l1off = ((q == 0) ? 65536 : 68608) + n * 16;
  const int l4off = (n < 4) ? (67584 + (q * 4 + n) * 16) : (68608 + n * 16);
  const int b2off = 70656 + q * 16;
  const int b3off = 71168 + q * 16;
  const int b4off = 71680 + q * 16;

  const f32x4 zf = {0.f, 0.f, 0.f, 0.f};

  float px[2][6] = {};
  int g = waveId;
  if (g < nGroups && q == 0) {
#pragma unroll
    for (int t = 0; t < 2; ++t) {
      const float* p = x + (g * 32 + t * 16 + n) * 6;
      f32x2 a = *(const f32x2*)p, b = *(const f32x2*)(p + 2), c = *(const f32x2*)(p + 4);
      px[t][0] = a.x; px[t][1] = a.y; px[t][2] = b.x;
      px[t][3] = b.y; px[t][4] = c.x; px[t][5] = c.y;
    }
  }

  for (; g < nGroups; g += totalWaves) {
    // ---- anti-hoist: launder the extras base every iteration ----
    uintptr_t wsl = (uintptr_t)ws;
    asm volatile("" : "+v"(wsl));  // opaque -> extras loads stay in the loop
    const char* wsv = (const char*)wsl;
    const short8* l1g = (const short8*)(wsv + l1off);   // + nt*16
    const short8* l4g = (const short8*)(wsv + l4off);   // + ks*16
    const f32x4* bias2 = (const f32x4*)(wsv + b2off);   // + nt*4
    const f32x4* bias3 = (const f32x4*)(wsv + b3off);   // + nt*4
    const f32x4* b4p   = (const f32x4*)(wsv + b4off);

    // ---- x -> layer-1 B frags (q==0: k0..5 = x, k6 = 1.0 bias slot) ----
    short8 xb[2];
#pragma unroll
    for (int t = 0; t < 2; ++t) {
      short8 v = {0, 0, 0, 0, 0, 0, 0, 0};
      if (q == 0) {
        v[0] = (short)bfr(px[t][0]); v[1] = (short)bfr(px[t][1]);
        v[2] = (short)bfr(px[t][2]); v[3] = (short)bfr(px[t][3]);
        v[4] = (short)bfr(px[t][4]); v[5] = (short)bfr(px[t][5]);
        v[6] = (short)0x3F80;  // bf16 1.0
      }
      xb[t] = v;
    }
    const int gn = g + totalWaves;
    if (gn < nGroups && q == 0) {
#pragma unroll
      for (int t = 0; t < 2; ++t) {
        const float* p = x + (gn * 32 + t * 16 + n) * 6;
        f32x2 a = *(const f32x2*)p, b = *(const f32x2*)(p + 2), c = *(const f32x2*)(p + 4);
        px[t][0] = a.x; px[t][1] = a.y; px[t][2] = b.x;
        px[t][3] = b.y; px[t][4] = c.x; px[t][5] = c.y;
      }
    }

    short8 B1[2][4], B2[2][4];

    // ---- layer 1 (compact frags from global/L2; bias in k-slot 6; C=0) ----
#pragma unroll
    for (int ntp = 0; ntp < 4; ++ntp) {
      const short8 w0 = l1g[(2 * ntp) * 16];
      const short8 w1 = l1g[(2 * ntp + 1) * 16];
      f32x4 a0[2], a1[2];
#pragma unroll
      for (int t = 0; t < 2; ++t) {
        a0[t] = MFMA(w0, xb[t], zf);
        a1[t] = MFMA(w1, xb[t], zf);
      }
#pragma unroll
      for (int t = 0; t < 2; ++t) B1[t][ntp] = pack4(a0[t], a1[t]);
    }

    // ---- layer 2 (W2 frags from LDS; bias as C at ks==0) ----
#pragma unroll
    for (int ntp = 0; ntp < 4; ++ntp) {
      f32x4 a0[2], a1[2];
#pragma unroll
      for (int ks = 0; ks < 4; ++ks) {
        const short8 w0 = *(const short8*)(w2b + (ks * 8 + 2 * ntp) * 512);
        const short8 w1 = *(const short8*)(w2b + (ks * 8 + 2 * ntp + 1) * 512);
        if (ks == 0) {
          const f32x4 bv0 = bias2[(2 * ntp) * 4];
          const f32x4 bv1 = bias2[(2 * ntp + 1) * 4];
#pragma unroll
          for (int t = 0; t < 2; ++t) {
            a0[t] = MFMA(w0, B1[t][0], bv0);
            a1[t] = MFMA(w1, B1[t][0], bv1);
          }
        } else {
#pragma unroll
          for (int t = 0; t < 2; ++t) {
            a0[t] = MFMA(w0, B1[t][ks], a0[t]);
            a1[t] = MFMA(w1, B1[t][ks], a1[t]);
          }
        }
      }
#pragma unroll
      for (int t = 0; t < 2; ++t) B2[t][ntp] = pack4(a0[t], a1[t]);
    }

    // ---- layer 3 (W3 frags from LDS) ----
#pragma unroll
    for (int ntp = 0; ntp < 4; ++ntp) {
      f32x4 a0[2], a1[2];
#pragma unroll
      for (int ks = 0; ks < 4; ++ks) {
        const short8 w0 = *(const short8*)(w3b + (ks * 8 + 2 * ntp) * 512);
        const short8 w1 = *(const short8*)(w3b + (ks * 8 + 2 * ntp + 1) * 512);
        if (ks == 0) {
          const f32x4 bv0 = bias3[(2 * ntp) * 4];
          const f32x4 bv1 = bias3[(2 * ntp + 1) * 4];
#pragma unroll
          for (int t = 0; t < 2; ++t) {
            a0[t] = MFMA(w0, B2[t][0], bv0);
            a1[t] = MFMA(w1, B2[t][0], bv1);
          }
        } else {
#pragma unroll
          for (int t = 0; t < 2; ++t) {
            a0[t] = MFMA(w0, B2[t][ks], a0[t]);
            a1[t] = MFMA(w1, B2[t][ks], a1[t]);
          }
        }
      }
#pragma unroll
      for (int t = 0; t < 2; ++t) B1[t][ntp] = pack4(a0[t], a1[t]);  // reuse B1
    }

    // ---- layer 4 (compact frags from global/L2; out rows at q==0) ----
    f32x4 o[2];
    {
      const f32x4 bv = b4p[0];
#pragma unroll
      for (int ks = 0; ks < 4; ++ks) {
        const short8 w = l4g[ks * 16];
        if (ks == 0) {
#pragma unroll
          for (int t = 0; t < 2; ++t) o[t] = MFMA(w, B1[t][0], bv);
        } else {
#pragma unroll
          for (int t = 0; t < 2; ++t) o[t] = MFMA(w, B1[t][ks], o[t]);
        }
      }
    }
    if (q == 0) {
#pragma unroll
      for (int t = 0; t < 2; ++t)
        *(f32x4*)(out + (g * 32 + t * 16 + n) * 4) = o[t];
    }
  }
}

extern "C" void kernel_launch(void* const* d_in, const int* in_sizes, int n_in,
                              void* d_out, int out_size, void* d_ws, size_t ws_size,
                              hipStream_t stream) {
  const float* x  = (const float*)d_in[0];
  const float* W1 = (const float*)d_in[1];
  const float* b1 = (const float*)d_in[2];
  const float* W2 = (const float*)d_in[3];
  const float* b2 = (const float*)d_in[4];
  const float* W3 = (const float*)d_in[5];
  const float* b3 = (const float*)d_in[6];
  const float* W4 = (const float*)d_in[7];
  const float* b4 = (const float*)d_in[8];
  float* out = (float*)d_out;

  const int N = in_sizes[0] / 6;
  const int nGroups = N / 32;  // 2 tiles of 16 rows per wave-iteration -> 32768

  nerf_stage<<<dim3(4), dim3(256), 0, stream>>>(W1, b1, W2, b2, W3, b3, W4, b4, d_ws);

  // 256 blocks x 8 waves = 2048 waves; 8 waves/CU (2/SIMD at the 128-reg tier)
  nerf_main<<<dim3(256), dim3(512), 0, stream>>>(x, out, d_ws, nGroups);
}